// Round 8
// baseline (254.819 us; speedup 1.0000x reference)
//
#include <hip/hip_runtime.h>
#include <hip/hip_bf16.h>
#include <math.h>

// MHA block: B=2, L=S=2048, D=768, H=12, hd=64. f32 in/out, bf16 MFMA inside.
// ws: Qp | Kp | Vt | Oatt (bf16, 6.29MB each) = 25.2MB. Weights staged f32->bf16
// in-register inside the GEMMs (no wcvt kernel, no bf16 weight intermediate).
// Pre-LN x (f32) lives in d_out; ln_kernel normalizes in place.
// SIZING FACT (r0-r6): resident blocks/CU = floor(64KB / LDS_Block_Size).
// ATTN FACTS: more blocks/CU thrashes L2 (r1/r2/r6); K/V reg-prefetch neutral
// (r7) -> loop is dependency-chain bound at 2 waves/SIMD. This round: 512-thr
// q-split-within-block doubles waves/SIMD at constant L2 footprint.

typedef unsigned short u16;
typedef unsigned int   u32;
typedef __bf16 bf16x8 __attribute__((ext_vector_type(8)));
typedef float  f32x4  __attribute__((ext_vector_type(4)));

#define DM   768
#define MR   4096          // B*L rows

#define LOG2E 1.44269504089f
#define SM_C  15.0f        // static softmax max-offset; scores ~N(0,1), safe
#define K1    (0.125f * LOG2E)

__device__ inline u16 bfbits(float f) {
    union { __bf16 b; u16 u; } x; x.b = (__bf16)f; return x.u;
}

// 8 contiguous f32 -> 8 bf16 packed in a uint4 (native cvt, compiler packs)
__device__ inline uint4 cvt8(const float* src) {
    const float4* p = reinterpret_cast<const float4*>(src);
    float4 a = p[0], b = p[1];
    union { __bf16 h[8]; uint4 v; } u;
    u.h[0] = (__bf16)a.x; u.h[1] = (__bf16)a.y; u.h[2] = (__bf16)a.z; u.h[3] = (__bf16)a.w;
    u.h[4] = (__bf16)b.x; u.h[5] = (__bf16)b.y; u.h[6] = (__bf16)b.z; u.h[7] = (__bf16)b.w;
    return u.v;
}

// two float4 -> uint4 of 8 bf16
__device__ inline uint4 cvt8v(float4 a, float4 b) {
    union { __bf16 h[8]; uint4 v; } u;
    u.h[0] = (__bf16)a.x; u.h[1] = (__bf16)a.y; u.h[2] = (__bf16)a.z; u.h[3] = (__bf16)a.w;
    u.h[4] = (__bf16)b.x; u.h[5] = (__bf16)b.y; u.h[6] = (__bf16)b.z; u.h[7] = (__bf16)b.w;
    return u.v;
}

// ---------------------------------------------------------------------------
// QKV projection, 64x64 tile, BK=64, grid (64,12,3) = 2304 blocks.
// A double-buffered from f32 input; B single-buffered, staged DIRECTLY from
// f32 weights with in-register cvt (wcvt folded in). 27648 B LDS ->
// 2 resident blocks/CU.
// mode 0/1: Q/K head-split  out[((b*12+h)*2048+l)*64+d]
// mode 2:   V transposed    out[((b*12+h)*64+d)*2048+l]
// ---------------------------------------------------------------------------
__global__ __launch_bounds__(256, 2) void gemm_qkv(
    const float* __restrict__ xq, const float* __restrict__ xk, const float* __restrict__ xv,
    const float* __restrict__ Wq, const float* __restrict__ Wk, const float* __restrict__ Wv,
    u16* __restrict__ oq, u16* __restrict__ ok, u16* __restrict__ ov)
{
    const int mode = blockIdx.z;
    const float* X  = (mode == 0) ? xq : (mode == 1) ? xk : xv;
    const float* Wf = (mode == 0) ? Wq : (mode == 1) ? Wk : Wv;
    u16* out        = (mode == 0) ? oq : (mode == 1) ? ok : ov;

    __shared__ __attribute__((aligned(16))) u16 As[2][64][72];   // 18432 B
    __shared__ __attribute__((aligned(16))) u16 Bs[64][72];      //  9216 B

    const int tid  = threadIdx.x;
    const int lane = tid & 63;
    const int w    = tid >> 6;
    const int wm   = (w >> 1) * 32;
    const int wn   = (w & 1) * 32;
    const int quad = lane >> 4;
    const int l16  = lane & 15;
    const int tm   = blockIdx.x * 64;
    const int tn   = blockIdx.y * 64;

    const int row0 = tid >> 3,         col0 = (tid & 7) * 8;          // rep 0
    const int row1 = (tid + 256) >> 3, col1 = ((tid + 256) & 7) * 8;  // rep 1

    const float* a0p = &X[(size_t)(tm + row0) * 768 + col0];
    const float* a1p = &X[(size_t)(tm + row1) * 768 + col1];
    const float* b0p = &Wf[(size_t)(tn + row0) * 768 + col0];
    const float* b1p = &Wf[(size_t)(tn + row1) * 768 + col1];

    f32x4 acc[2][2] = {};

    // prologue: A(0) into As[0]; B(0) into regs (f32)
    *reinterpret_cast<uint4*>(&As[0][row0][col0]) = cvt8(a0p);
    *reinterpret_cast<uint4*>(&As[0][row1][col1]) = cvt8(a1p);
    float4 bf0a = *reinterpret_cast<const float4*>(b0p);
    float4 bf0b = *reinterpret_cast<const float4*>(b0p + 4);
    float4 bf1a = *reinterpret_cast<const float4*>(b1p);
    float4 bf1b = *reinterpret_cast<const float4*>(b1p + 4);

    for (int kt = 0; kt < 12; kt++) {
        const int cur = kt & 1;
        if (kt) __syncthreads();             // all waves done reading Bs(kt-1)
        *reinterpret_cast<uint4*>(&Bs[row0][col0]) = cvt8v(bf0a, bf0b);
        *reinterpret_cast<uint4*>(&Bs[row1][col1]) = cvt8v(bf1a, bf1b);
        __syncthreads();                     // Bs(kt) + As[cur] ready

        // issue next tile's global loads (in flight across compute)
        float4 af0a, af0b, af1a, af1b;
        if (kt < 11) {
            const int ko = (kt + 1) * 64;
            af0a = *reinterpret_cast<const float4*>(a0p + ko);
            af0b = *reinterpret_cast<const float4*>(a0p + ko + 4);
            af1a = *reinterpret_cast<const float4*>(a1p + ko);
            af1b = *reinterpret_cast<const float4*>(a1p + ko + 4);
            bf0a = *reinterpret_cast<const float4*>(b0p + ko);
            bf0b = *reinterpret_cast<const float4*>(b0p + ko + 4);
            bf1a = *reinterpret_cast<const float4*>(b1p + ko);
            bf1b = *reinterpret_cast<const float4*>(b1p + ko + 4);
        }

        // compute on As[cur], Bs
        #pragma unroll
        for (int kk = 0; kk < 2; kk++) {
            bf16x8 a0 = *reinterpret_cast<const bf16x8*>(&As[cur][wm + l16     ][kk*32 + quad*8]);
            bf16x8 a1 = *reinterpret_cast<const bf16x8*>(&As[cur][wm + 16 + l16][kk*32 + quad*8]);
            bf16x8 b0 = *reinterpret_cast<const bf16x8*>(&Bs[wn + l16     ][kk*32 + quad*8]);
            bf16x8 b1 = *reinterpret_cast<const bf16x8*>(&Bs[wn + 16 + l16][kk*32 + quad*8]);
            acc[0][0] = __builtin_amdgcn_mfma_f32_16x16x32_bf16(a0, b0, acc[0][0], 0, 0, 0);
            acc[0][1] = __builtin_amdgcn_mfma_f32_16x16x32_bf16(a0, b1, acc[0][1], 0, 0, 0);
            acc[1][0] = __builtin_amdgcn_mfma_f32_16x16x32_bf16(a1, b0, acc[1][0], 0, 0, 0);
            acc[1][1] = __builtin_amdgcn_mfma_f32_16x16x32_bf16(a1, b1, acc[1][1], 0, 0, 0);
        }

        // cvt + write A(kt+1) into the other buffer
        if (kt < 11) {
            const int nxt = cur ^ 1;
            *reinterpret_cast<uint4*>(&As[nxt][row0][col0]) = cvt8v(af0a, af0b);
            *reinterpret_cast<uint4*>(&As[nxt][row1][col1]) = cvt8v(af1a, af1b);
        }
    }

    #pragma unroll
    for (int i = 0; i < 2; i++)
        #pragma unroll
        for (int j = 0; j < 2; j++)
            #pragma unroll
            for (int r = 0; r < 4; r++) {
                int gm = tm + wm + i * 16 + quad * 4 + r;   // row (b*2048+l)
                int gn = tn + wn + j * 16 + l16;            // col (h*64+d)
                int b = gm >> 11, l = gm & 2047;
                int h = gn >> 6,  d = gn & 63;
                u16 bv = bfbits(acc[i][j][r]);
                if (mode == 2)
                    out[((size_t)(b * 12 + h) * 64 + d) * 2048 + l] = bv;
                else
                    out[((size_t)(b * 12 + h) * 2048 + l) * 64 + d] = bv;
            }
}

// ---------------------------------------------------------------------------
// out-proj: x[m][n] = Oatt[m]·W[n] + bias[n] + q[m][n]  (f32 -> d_out)
// 64x64 tile, grid (64,12); A (bf16 Oa) dbuf, B staged from f32 W directly.
// ---------------------------------------------------------------------------
__global__ __launch_bounds__(256, 2) void gemm_out(
    const u16* __restrict__ Oa, const float* __restrict__ Wf,
    const float* __restrict__ bias, const float* __restrict__ resid,
    float* __restrict__ Xb)
{
    __shared__ __attribute__((aligned(16))) u16 As[2][64][72];
    __shared__ __attribute__((aligned(16))) u16 Bs[64][72];

    const int tid  = threadIdx.x;
    const int lane = tid & 63;
    const int w    = tid >> 6;
    const int wm   = (w >> 1) * 32;
    const int wn   = (w & 1) * 32;
    const int quad = lane >> 4;
    const int l16  = lane & 15;
    const int tm   = blockIdx.x * 64;
    const int tn   = blockIdx.y * 64;

    const int row0 = tid >> 3,         col0 = (tid & 7) * 8;
    const int row1 = (tid + 256) >> 3, col1 = ((tid + 256) & 7) * 8;

    const u16*   a0p = &Oa[(size_t)(tm + row0) * 768 + col0];
    const u16*   a1p = &Oa[(size_t)(tm + row1) * 768 + col1];
    const float* b0p = &Wf[(size_t)(tn + row0) * 768 + col0];
    const float* b1p = &Wf[(size_t)(tn + row1) * 768 + col1];

    f32x4 acc[2][2] = {};

    *reinterpret_cast<uint4*>(&As[0][row0][col0]) = *reinterpret_cast<const uint4*>(a0p);
    *reinterpret_cast<uint4*>(&As[0][row1][col1]) = *reinterpret_cast<const uint4*>(a1p);
    float4 bf0a = *reinterpret_cast<const float4*>(b0p);
    float4 bf0b = *reinterpret_cast<const float4*>(b0p + 4);
    float4 bf1a = *reinterpret_cast<const float4*>(b1p);
    float4 bf1b = *reinterpret_cast<const float4*>(b1p + 4);

    for (int kt = 0; kt < 12; kt++) {
        const int cur = kt & 1;
        if (kt) __syncthreads();
        *reinterpret_cast<uint4*>(&Bs[row0][col0]) = cvt8v(bf0a, bf0b);
        *reinterpret_cast<uint4*>(&Bs[row1][col1]) = cvt8v(bf1a, bf1b);
        __syncthreads();

        uint4 at0, at1;
        if (kt < 11) {
            const int ko = (kt + 1) * 64;
            at0 = *reinterpret_cast<const uint4*>(a0p + ko);
            at1 = *reinterpret_cast<const uint4*>(a1p + ko);
            bf0a = *reinterpret_cast<const float4*>(b0p + ko);
            bf0b = *reinterpret_cast<const float4*>(b0p + ko + 4);
            bf1a = *reinterpret_cast<const float4*>(b1p + ko);
            bf1b = *reinterpret_cast<const float4*>(b1p + ko + 4);
        }

        #pragma unroll
        for (int kk = 0; kk < 2; kk++) {
            bf16x8 a0 = *reinterpret_cast<const bf16x8*>(&As[cur][wm + l16     ][kk*32 + quad*8]);
            bf16x8 a1 = *reinterpret_cast<const bf16x8*>(&As[cur][wm + 16 + l16][kk*32 + quad*8]);
            bf16x8 b0 = *reinterpret_cast<const bf16x8*>(&Bs[wn + l16     ][kk*32 + quad*8]);
            bf16x8 b1 = *reinterpret_cast<const bf16x8*>(&Bs[wn + 16 + l16][kk*32 + quad*8]);
            acc[0][0] = __builtin_amdgcn_mfma_f32_16x16x32_bf16(a0, b0, acc[0][0], 0, 0, 0);
            acc[0][1] = __builtin_amdgcn_mfma_f32_16x16x32_bf16(a0, b1, acc[0][1], 0, 0, 0);
            acc[1][0] = __builtin_amdgcn_mfma_f32_16x16x32_bf16(a1, b0, acc[1][0], 0, 0, 0);
            acc[1][1] = __builtin_amdgcn_mfma_f32_16x16x32_bf16(a1, b1, acc[1][1], 0, 0, 0);
        }

        if (kt < 11) {
            const int nxt = cur ^ 1;
            *reinterpret_cast<uint4*>(&As[nxt][row0][col0]) = at0;
            *reinterpret_cast<uint4*>(&As[nxt][row1][col1]) = at1;
        }
    }

    #pragma unroll
    for (int i = 0; i < 2; i++)
        #pragma unroll
        for (int j = 0; j < 2; j++)
            #pragma unroll
            for (int r = 0; r < 4; r++) {
                int gm = tm + wm + i * 16 + quad * 4 + r;
                int gn = tn + wn + j * 16 + l16;
                Xb[(size_t)gm * 768 + gn] = acc[i][j][r] + bias[gn] + resid[(size_t)gm * 768 + gn];
            }
}

// ---------------------------------------------------------------------------
// Flash attention, 512 threads: q-split WITHIN the block. 8 waves: wave w
// owns key-group wk=w&3 (32 keys) and q-half wq=w>>2 (2 of 4 qb). Same LDS
// (28672B -> 2 blocks/CU, same L2 footprint as the 60us baseline) but
// 16 waves/CU instead of 8 -> doubles TLP against the serial chain
// (QK -> exp -> P LDS roundtrip -> PV). Main loop stays barrier-free:
// the two waves sharing Ps[wk] touch disjoint row halves.
// Epilogue: 4 phases; at phase p the two wk==p waves (disjoint rows) merge.
// ---------------------------------------------------------------------------
__global__ __launch_bounds__(512, 4) void attn(
    const u16* __restrict__ Qp, const u16* __restrict__ Kp, const u16* __restrict__ Vt,
    const int* __restrict__ amask, u16* __restrict__ Oatt)
{
    __shared__ __attribute__((aligned(16))) unsigned char smem[4 * 64 * 40 * 2 + 2048 * 4];
    u16 (*Ps)[64][40] = reinterpret_cast<u16(*)[64][40]>(smem);        // 20480 B
    float* maskC = reinterpret_cast<float*>(smem + 20480);             // 8192 B
    float (*Obuf)[68] = reinterpret_cast<float(*)[68]>(smem);          // epilogue alias, 17408 B

    const int tid  = threadIdx.x;
    const int lane = tid & 63;
    const int w    = tid >> 6;     // 0..7
    const int wk   = w & 3;        // key group (32 keys)
    const int wq   = w >> 2;       // q half (qb pair)
    const int quad = lane >> 4;
    const int l16  = lane & 15;
    const int qt = blockIdx.x;     // 0..31
    const int h  = blockIdx.y;     // 0..11
    const int b  = blockIdx.z;     // 0..1

    // one-time mask preload
    #pragma unroll
    for (int i = 0; i < 4; i++) {
        int s = tid + i * 512;
        maskC[s] = amask[b * 2048 + s] ? (-SM_C * LOG2E) : -2.0e6f;
    }
    __syncthreads();

    const u16* Qbase = Qp + ((size_t)(b * 12 + h) * 2048 + qt * 64) * 64;
    const u16* Kb2   = Kp + (size_t)(b * 12 + h) * 2048 * 64 + (size_t)wk * 32 * 64;
    const u16* Vb2   = Vt + (size_t)(b * 12 + h) * 64 * 2048 + (size_t)wk * 32;

    // Q fragments for THIS wave's 2 q-blocks (global qb = wq*2 + q)
    bf16x8 qfrag[2][2];
    #pragma unroll
    for (int q = 0; q < 2; q++)
        #pragma unroll
        for (int kk = 0; kk < 2; kk++)
            qfrag[q][kk] = *reinterpret_cast<const bf16x8*>(
                &Qbase[((wq * 2 + q) * 16 + l16) * 64 + kk * 32 + quad * 8]);

    // ones B-fragment: B[n=0][k]=1 -> C col 0 = rowsum(P)
    bf16x8 onesf = {};
    if (l16 == 0) {
        #pragma unroll
        for (int i = 0; i < 8; i++) onesf[i] = (__bf16)1.0f;
    }

    f32x4 oacc[2][4] = {};   // [q][d-block] partial over this wave's keys
    f32x4 sacc[2]    = {};   // [q] partial rowsums (col 0)

    // preload st=0 K and V fragments
    bf16x8 kf[2][2], vf[4];
    #pragma unroll
    for (int ct = 0; ct < 2; ct++)
        #pragma unroll
        for (int kk = 0; kk < 2; kk++)
            kf[ct][kk] = *reinterpret_cast<const bf16x8*>(
                &Kb2[(size_t)(ct * 16 + l16) * 64 + kk * 32 + quad * 8]);
    #pragma unroll
    for (int cd = 0; cd < 4; cd++)
        vf[cd] = *reinterpret_cast<const bf16x8*>(
            &Vb2[(size_t)(cd * 16 + l16) * 2048 + quad * 8]);

    for (int st = 0; st < 16; st++) {
        const int stn = (st + 1) & 15;   // wrap: st=15 reloads st=0 (unused, in-bounds)

        // S^T = K·Q^T, ct-outer; reload kf[ct] right after its last use
        #pragma unroll
        for (int ct = 0; ct < 2; ct++) {
            f32x4 sv[2];
            #pragma unroll
            for (int q = 0; q < 2; q++) {
                f32x4 s = {};
                s = __builtin_amdgcn_mfma_f32_16x16x32_bf16(kf[ct][0], qfrag[q][0], s, 0, 0, 0);
                s = __builtin_amdgcn_mfma_f32_16x16x32_bf16(kf[ct][1], qfrag[q][1], s, 0, 0, 0);
                sv[q] = s;
            }
            // kf[ct] dead -> issue next-tile loads into the same registers
            #pragma unroll
            for (int kk = 0; kk < 2; kk++)
                kf[ct][kk] = *reinterpret_cast<const bf16x8*>(
                    &Kb2[(size_t)(stn * 128 + ct * 16 + l16) * 64 + kk * 32 + quad * 8]);

            f32x4 cc = *reinterpret_cast<const f32x4*>(
                &maskC[st * 128 + wk * 32 + ct * 16 + quad * 4]);
            #pragma unroll
            for (int q = 0; q < 2; q++) {
                union { u16 h[4]; uint2 v2; } pk;
                #pragma unroll
                for (int r = 0; r < 4; r++)
                    pk.h[r] = bfbits(__builtin_amdgcn_exp2f(__builtin_fmaf(sv[q][r], K1, cc[r])));
                *reinterpret_cast<uint2*>(
                    &Ps[wk][(wq * 2 + q) * 16 + l16][ct * 16 + quad * 4]) = pk.v2;
            }
        }

        // read P as A-fragments (K-dim = wave's 32 keys); accumulate partials
        bf16x8 pf[2];
        #pragma unroll
        for (int q = 0; q < 2; q++)
            pf[q] = *reinterpret_cast<const bf16x8*>(
                &Ps[wk][(wq * 2 + q) * 16 + l16][quad * 8]);
        #pragma unroll
        for (int q = 0; q < 2; q++)
            sacc[q] = __builtin_amdgcn_mfma_f32_16x16x32_bf16(pf[q], onesf, sacc[q], 0, 0, 0);
        #pragma unroll
        for (int q = 0; q < 2; q++)
            #pragma unroll
            for (int cd = 0; cd < 4; cd++)
                oacc[q][cd] = __builtin_amdgcn_mfma_f32_16x16x32_bf16(pf[q], vf[cd], oacc[q][cd], 0, 0, 0);

        // vf dead -> issue next-tile V loads into the same registers
        #pragma unroll
        for (int cd = 0; cd < 4; cd++)
            vf[cd] = *reinterpret_cast<const bf16x8*>(
                &Vb2[(size_t)(cd * 16 + l16) * 2048 + stn * 128 + quad * 8]);
    }

    // ---- cross-wave reduction (Obuf aliases Ps). Phase p: both wk==p waves
    // (wq=0 rows 0-31, wq=1 rows 32-63, disjoint) write/accumulate. ----
    __syncthreads();
    for (int wv = 0; wv < 4; wv++) {
        if (wk == wv) {
            #pragma unroll
            for (int q = 0; q < 2; q++) {
                const int rowb = (wq * 2 + q) * 16;
                #pragma unroll
                for (int cd = 0; cd < 4; cd++)
                    #pragma unroll
                    for (int r = 0; r < 4; r++) {
                        float* cell = &Obuf[rowb + quad * 4 + r][cd * 16 + l16];
                        if (wv == 0) *cell = oacc[q][cd][r];
                        else         *cell += oacc[q][cd][r];
                    }
                if (l16 == 0) {
                    #pragma unroll
                    for (int r = 0; r < 4; r++) {
                        float* cell = &Obuf[rowb + quad * 4 + r][64];
                        if (wv == 0) *cell = sacc[q][r];
                        else         *cell += sacc[q][r];
                    }
                }
            }
        }
        __syncthreads();
    }

    // normalize + store (vectorized 4 cols per thread; 1024 units, 512 thr)
    #pragma unroll
    for (int g = 0; g < 2; g++) {
        int unit = tid + g * 512;          // 0..1023
        int row = unit >> 4;               // 0..63
        int c4  = (unit & 15) * 4;
        float rinv = 1.0f / Obuf[row][64];
        union { u16 h[4]; uint2 v; } o;
        #pragma unroll
        for (int j = 0; j < 4; j++)
            o.h[j] = bfbits(Obuf[row][c4 + j] * rinv);
        *reinterpret_cast<uint2*>(
            &Oatt[(size_t)(b * 2048 + qt * 64 + row) * 768 + h * 64 + c4]) = o.v;
    }
}

// ---------------------------------------------------------------------------
// LayerNorm over D=768: one WAVE per row (no cross-wave reduce, no barrier),
// float4 vectorized. 4 rows/block, grid 1024.
// ---------------------------------------------------------------------------
__global__ __launch_bounds__(256) void ln_kernel(
    float* __restrict__ X, const float* __restrict__ gamma,
    const float* __restrict__ beta)
{
    const int tid  = threadIdx.x;
    const int w    = tid >> 6;
    const int lane = tid & 63;
    const int row  = blockIdx.x * 4 + w;
    float* xr = X + (size_t)row * 768;

    float4 v[3];
    float s = 0.f, s2 = 0.f;
    #pragma unroll
    for (int i = 0; i < 3; i++) {
        v[i] = *reinterpret_cast<const float4*>(&xr[i * 256 + lane * 4]);
        s  += v[i].x + v[i].y + v[i].z + v[i].w;
        s2 += v[i].x * v[i].x + v[i].y * v[i].y + v[i].z * v[i].z + v[i].w * v[i].w;
    }
    #pragma unroll
    for (int off = 32; off >= 1; off >>= 1) {
        s  += __shfl_xor(s,  off, 64);
        s2 += __shfl_xor(s2, off, 64);
    }
    float mu  = s * (1.0f / 768.0f);
    float var = s2 * (1.0f / 768.0f) - mu * mu;
    float rstd = rsqrtf(var + 1e-5f);
    #pragma unroll
    for (int i = 0; i < 3; i++) {
        int c = i * 256 + lane * 4;
        float4 g  = *reinterpret_cast<const float4*>(&gamma[c]);
        float4 bt = *reinterpret_cast<const float4*>(&beta[c]);
        float4 o;
        o.x = (v[i].x - mu) * rstd * g.x + bt.x;
        o.y = (v[i].y - mu) * rstd * g.y + bt.y;
        o.z = (v[i].z - mu) * rstd * g.z + bt.z;
        o.w = (v[i].w - mu) * rstd * g.w + bt.w;
        *reinterpret_cast<float4*>(&xr[c]) = o;
    }
}

extern "C" void kernel_launch(void* const* d_in, const int* in_sizes, int n_in,
                              void* d_out, int out_size, void* d_ws, size_t ws_size,
                              hipStream_t stream)
{
    const float* q   = (const float*)d_in[0];
    const float* k   = (const float*)d_in[1];
    const float* v   = (const float*)d_in[2];
    const int*   am  = (const int*)d_in[3];
    const float* Wq  = (const float*)d_in[4];
    const float* Wk  = (const float*)d_in[5];
    const float* Wv  = (const float*)d_in[6];
    const float* W   = (const float*)d_in[7];
    const float* bb  = (const float*)d_in[8];
    const float* gam = (const float*)d_in[9];
    const float* bet = (const float*)d_in[10];

    u16* Qp  = (u16*)d_ws;
    u16* Kp  = Qp + (size_t)MR * DM;
    u16* Vt  = Kp + (size_t)MR * DM;
    u16* Oa  = Vt + (size_t)MR * DM;
    float* Xb = (float*)d_out;                     // pre-LN x; LN in place

    gemm_qkv<<<dim3(64, 12, 3), 256, 0, stream>>>(q, k, v, Wq, Wk, Wv, Qp, Kp, Vt);
    attn<<<dim3(32, 12, 2), 512, 0, stream>>>(Qp, Kp, Vt, am, Oa);
    gemm_out<<<dim3(64, 12), 256, 0, stream>>>(Oa, W, bb, q, Xb);
    ln_kernel<<<1024, 256, 0, stream>>>(Xb, gam, bet);
}

// Round 9
// 216.422 us; speedup vs baseline: 1.1774x; 1.1774x over previous
//
#include <hip/hip_runtime.h>
#include <hip/hip_bf16.h>
#include <math.h>

// MHA block: B=2, L=S=2048, D=768, H=12, hd=64. f32 in/out, bf16 MFMA inside.
// ws: Qp | Kp | Vt | Oatt (bf16, 6.29MB each) = 25.2MB. Weights staged f32->bf16
// in-register inside the GEMMs (wcvt folded; r8: rest-of-pipeline 156.3->153.9).
// Pre-LN x (f32) lives in d_out; ln_kernel normalizes in place.
// ATTN LEDGER (r0-r8): time tracks total K/V load traffic. Key-split 4-wave
// 256-thr block = minimal loads = 60us floor. Load-doubling variants (r1 q-split
// blocks, r8 q-split waves) both ~100us. Occupancy/prefetch/setprio: neutral or
// negative. Keep r7 attn exactly.

typedef unsigned short u16;
typedef unsigned int   u32;
typedef __bf16 bf16x8 __attribute__((ext_vector_type(8)));
typedef float  f32x4  __attribute__((ext_vector_type(4)));

#define DM   768
#define MR   4096          // B*L rows

#define LOG2E 1.44269504089f
#define SM_C  15.0f        // static softmax max-offset; scores ~N(0,1), safe
#define K1    (0.125f * LOG2E)

__device__ inline u16 bfbits(float f) {
    union { __bf16 b; u16 u; } x; x.b = (__bf16)f; return x.u;
}

// 8 contiguous f32 -> 8 bf16 packed in a uint4 (native cvt, compiler packs)
__device__ inline uint4 cvt8(const float* src) {
    const float4* p = reinterpret_cast<const float4*>(src);
    float4 a = p[0], b = p[1];
    union { __bf16 h[8]; uint4 v; } u;
    u.h[0] = (__bf16)a.x; u.h[1] = (__bf16)a.y; u.h[2] = (__bf16)a.z; u.h[3] = (__bf16)a.w;
    u.h[4] = (__bf16)b.x; u.h[5] = (__bf16)b.y; u.h[6] = (__bf16)b.z; u.h[7] = (__bf16)b.w;
    return u.v;
}

// two float4 -> uint4 of 8 bf16
__device__ inline uint4 cvt8v(float4 a, float4 b) {
    union { __bf16 h[8]; uint4 v; } u;
    u.h[0] = (__bf16)a.x; u.h[1] = (__bf16)a.y; u.h[2] = (__bf16)a.z; u.h[3] = (__bf16)a.w;
    u.h[4] = (__bf16)b.x; u.h[5] = (__bf16)b.y; u.h[6] = (__bf16)b.z; u.h[7] = (__bf16)b.w;
    return u.v;
}

// ---------------------------------------------------------------------------
// QKV projection, 64x64 tile, BK=64, grid (64,12,3) = 2304 blocks.
// A double-buffered from f32 input; B single-buffered, staged DIRECTLY from
// f32 weights with in-register cvt. 27648 B LDS -> 2 resident blocks/CU.
// mode 0/1: Q/K head-split  out[((b*12+h)*2048+l)*64+d]
// mode 2:   V transposed    out[((b*12+h)*64+d)*2048+l]
// ---------------------------------------------------------------------------
__global__ __launch_bounds__(256, 2) void gemm_qkv(
    const float* __restrict__ xq, const float* __restrict__ xk, const float* __restrict__ xv,
    const float* __restrict__ Wq, const float* __restrict__ Wk, const float* __restrict__ Wv,
    u16* __restrict__ oq, u16* __restrict__ ok, u16* __restrict__ ov)
{
    const int mode = blockIdx.z;
    const float* X  = (mode == 0) ? xq : (mode == 1) ? xk : xv;
    const float* Wf = (mode == 0) ? Wq : (mode == 1) ? Wk : Wv;
    u16* out        = (mode == 0) ? oq : (mode == 1) ? ok : ov;

    __shared__ __attribute__((aligned(16))) u16 As[2][64][72];   // 18432 B
    __shared__ __attribute__((aligned(16))) u16 Bs[64][72];      //  9216 B

    const int tid  = threadIdx.x;
    const int lane = tid & 63;
    const int w    = tid >> 6;
    const int wm   = (w >> 1) * 32;
    const int wn   = (w & 1) * 32;
    const int quad = lane >> 4;
    const int l16  = lane & 15;
    const int tm   = blockIdx.x * 64;
    const int tn   = blockIdx.y * 64;

    const int row0 = tid >> 3,         col0 = (tid & 7) * 8;          // rep 0
    const int row1 = (tid + 256) >> 3, col1 = ((tid + 256) & 7) * 8;  // rep 1

    const float* a0p = &X[(size_t)(tm + row0) * 768 + col0];
    const float* a1p = &X[(size_t)(tm + row1) * 768 + col1];
    const float* b0p = &Wf[(size_t)(tn + row0) * 768 + col0];
    const float* b1p = &Wf[(size_t)(tn + row1) * 768 + col1];

    f32x4 acc[2][2] = {};

    // prologue: A(0) into As[0]; B(0) into regs (f32)
    *reinterpret_cast<uint4*>(&As[0][row0][col0]) = cvt8(a0p);
    *reinterpret_cast<uint4*>(&As[0][row1][col1]) = cvt8(a1p);
    float4 bf0a = *reinterpret_cast<const float4*>(b0p);
    float4 bf0b = *reinterpret_cast<const float4*>(b0p + 4);
    float4 bf1a = *reinterpret_cast<const float4*>(b1p);
    float4 bf1b = *reinterpret_cast<const float4*>(b1p + 4);

    for (int kt = 0; kt < 12; kt++) {
        const int cur = kt & 1;
        if (kt) __syncthreads();             // all waves done reading Bs(kt-1)
        *reinterpret_cast<uint4*>(&Bs[row0][col0]) = cvt8v(bf0a, bf0b);
        *reinterpret_cast<uint4*>(&Bs[row1][col1]) = cvt8v(bf1a, bf1b);
        __syncthreads();                     // Bs(kt) + As[cur] ready

        // issue next tile's global loads (in flight across compute)
        float4 af0a, af0b, af1a, af1b;
        if (kt < 11) {
            const int ko = (kt + 1) * 64;
            af0a = *reinterpret_cast<const float4*>(a0p + ko);
            af0b = *reinterpret_cast<const float4*>(a0p + ko + 4);
            af1a = *reinterpret_cast<const float4*>(a1p + ko);
            af1b = *reinterpret_cast<const float4*>(a1p + ko + 4);
            bf0a = *reinterpret_cast<const float4*>(b0p + ko);
            bf0b = *reinterpret_cast<const float4*>(b0p + ko + 4);
            bf1a = *reinterpret_cast<const float4*>(b1p + ko);
            bf1b = *reinterpret_cast<const float4*>(b1p + ko + 4);
        }

        // compute on As[cur], Bs
        #pragma unroll
        for (int kk = 0; kk < 2; kk++) {
            bf16x8 a0 = *reinterpret_cast<const bf16x8*>(&As[cur][wm + l16     ][kk*32 + quad*8]);
            bf16x8 a1 = *reinterpret_cast<const bf16x8*>(&As[cur][wm + 16 + l16][kk*32 + quad*8]);
            bf16x8 b0 = *reinterpret_cast<const bf16x8*>(&Bs[wn + l16     ][kk*32 + quad*8]);
            bf16x8 b1 = *reinterpret_cast<const bf16x8*>(&Bs[wn + 16 + l16][kk*32 + quad*8]);
            acc[0][0] = __builtin_amdgcn_mfma_f32_16x16x32_bf16(a0, b0, acc[0][0], 0, 0, 0);
            acc[0][1] = __builtin_amdgcn_mfma_f32_16x16x32_bf16(a0, b1, acc[0][1], 0, 0, 0);
            acc[1][0] = __builtin_amdgcn_mfma_f32_16x16x32_bf16(a1, b0, acc[1][0], 0, 0, 0);
            acc[1][1] = __builtin_amdgcn_mfma_f32_16x16x32_bf16(a1, b1, acc[1][1], 0, 0, 0);
        }

        // cvt + write A(kt+1) into the other buffer
        if (kt < 11) {
            const int nxt = cur ^ 1;
            *reinterpret_cast<uint4*>(&As[nxt][row0][col0]) = cvt8v(af0a, af0b);
            *reinterpret_cast<uint4*>(&As[nxt][row1][col1]) = cvt8v(af1a, af1b);
        }
    }

    #pragma unroll
    for (int i = 0; i < 2; i++)
        #pragma unroll
        for (int j = 0; j < 2; j++)
            #pragma unroll
            for (int r = 0; r < 4; r++) {
                int gm = tm + wm + i * 16 + quad * 4 + r;   // row (b*2048+l)
                int gn = tn + wn + j * 16 + l16;            // col (h*64+d)
                int b = gm >> 11, l = gm & 2047;
                int h = gn >> 6,  d = gn & 63;
                u16 bv = bfbits(acc[i][j][r]);
                if (mode == 2)
                    out[((size_t)(b * 12 + h) * 64 + d) * 2048 + l] = bv;
                else
                    out[((size_t)(b * 12 + h) * 2048 + l) * 64 + d] = bv;
            }
}

// ---------------------------------------------------------------------------
// out-proj: x[m][n] = Oatt[m]·W[n] + bias[n] + q[m][n]  (f32 -> d_out)
// 64x64 tile, grid (64,12); A (bf16 Oa) dbuf, B staged from f32 W directly.
// ---------------------------------------------------------------------------
__global__ __launch_bounds__(256, 2) void gemm_out(
    const u16* __restrict__ Oa, const float* __restrict__ Wf,
    const float* __restrict__ bias, const float* __restrict__ resid,
    float* __restrict__ Xb)
{
    __shared__ __attribute__((aligned(16))) u16 As[2][64][72];
    __shared__ __attribute__((aligned(16))) u16 Bs[64][72];

    const int tid  = threadIdx.x;
    const int lane = tid & 63;
    const int w    = tid >> 6;
    const int wm   = (w >> 1) * 32;
    const int wn   = (w & 1) * 32;
    const int quad = lane >> 4;
    const int l16  = lane & 15;
    const int tm   = blockIdx.x * 64;
    const int tn   = blockIdx.y * 64;

    const int row0 = tid >> 3,         col0 = (tid & 7) * 8;
    const int row1 = (tid + 256) >> 3, col1 = ((tid + 256) & 7) * 8;

    const u16*   a0p = &Oa[(size_t)(tm + row0) * 768 + col0];
    const u16*   a1p = &Oa[(size_t)(tm + row1) * 768 + col1];
    const float* b0p = &Wf[(size_t)(tn + row0) * 768 + col0];
    const float* b1p = &Wf[(size_t)(tn + row1) * 768 + col1];

    f32x4 acc[2][2] = {};

    *reinterpret_cast<uint4*>(&As[0][row0][col0]) = *reinterpret_cast<const uint4*>(a0p);
    *reinterpret_cast<uint4*>(&As[0][row1][col1]) = *reinterpret_cast<const uint4*>(a1p);
    float4 bf0a = *reinterpret_cast<const float4*>(b0p);
    float4 bf0b = *reinterpret_cast<const float4*>(b0p + 4);
    float4 bf1a = *reinterpret_cast<const float4*>(b1p);
    float4 bf1b = *reinterpret_cast<const float4*>(b1p + 4);

    for (int kt = 0; kt < 12; kt++) {
        const int cur = kt & 1;
        if (kt) __syncthreads();
        *reinterpret_cast<uint4*>(&Bs[row0][col0]) = cvt8v(bf0a, bf0b);
        *reinterpret_cast<uint4*>(&Bs[row1][col1]) = cvt8v(bf1a, bf1b);
        __syncthreads();

        uint4 at0, at1;
        if (kt < 11) {
            const int ko = (kt + 1) * 64;
            at0 = *reinterpret_cast<const uint4*>(a0p + ko);
            at1 = *reinterpret_cast<const uint4*>(a1p + ko);
            bf0a = *reinterpret_cast<const float4*>(b0p + ko);
            bf0b = *reinterpret_cast<const float4*>(b0p + ko + 4);
            bf1a = *reinterpret_cast<const float4*>(b1p + ko);
            bf1b = *reinterpret_cast<const float4*>(b1p + ko + 4);
        }

        #pragma unroll
        for (int kk = 0; kk < 2; kk++) {
            bf16x8 a0 = *reinterpret_cast<const bf16x8*>(&As[cur][wm + l16     ][kk*32 + quad*8]);
            bf16x8 a1 = *reinterpret_cast<const bf16x8*>(&As[cur][wm + 16 + l16][kk*32 + quad*8]);
            bf16x8 b0 = *reinterpret_cast<const bf16x8*>(&Bs[wn + l16     ][kk*32 + quad*8]);
            bf16x8 b1 = *reinterpret_cast<const bf16x8*>(&Bs[wn + 16 + l16][kk*32 + quad*8]);
            acc[0][0] = __builtin_amdgcn_mfma_f32_16x16x32_bf16(a0, b0, acc[0][0], 0, 0, 0);
            acc[0][1] = __builtin_amdgcn_mfma_f32_16x16x32_bf16(a0, b1, acc[0][1], 0, 0, 0);
            acc[1][0] = __builtin_amdgcn_mfma_f32_16x16x32_bf16(a1, b0, acc[1][0], 0, 0, 0);
            acc[1][1] = __builtin_amdgcn_mfma_f32_16x16x32_bf16(a1, b1, acc[1][1], 0, 0, 0);
        }

        if (kt < 11) {
            const int nxt = cur ^ 1;
            *reinterpret_cast<uint4*>(&As[nxt][row0][col0]) = at0;
            *reinterpret_cast<uint4*>(&As[nxt][row1][col1]) = at1;
        }
    }

    #pragma unroll
    for (int i = 0; i < 2; i++)
        #pragma unroll
        for (int j = 0; j < 2; j++)
            #pragma unroll
            for (int r = 0; r < 4; r++) {
                int gm = tm + wm + i * 16 + quad * 4 + r;
                int gn = tn + wn + j * 16 + l16;
                Xb[(size_t)gm * 768 + gn] = acc[i][j][r] + bias[gn] + resid[(size_t)gm * 768 + gn];
            }
}

// ---------------------------------------------------------------------------
// Flash attention: r7 version exactly (measured 59.8us). 64 q-rows/block,
// key-split 4 waves (minimal K/V load count), mask in LDS, ct-outer in-place
// K/V register prefetch, barrier-free main loop, Obuf stride 68 epilogue.
// ---------------------------------------------------------------------------
__global__ __launch_bounds__(256, 3) void attn(
    const u16* __restrict__ Qp, const u16* __restrict__ Kp, const u16* __restrict__ Vt,
    const int* __restrict__ amask, u16* __restrict__ Oatt)
{
    __shared__ __attribute__((aligned(16))) unsigned char smem[4 * 64 * 40 * 2 + 2048 * 4];
    u16 (*Ps)[64][40] = reinterpret_cast<u16(*)[64][40]>(smem);        // 20480 B
    float* maskC = reinterpret_cast<float*>(smem + 20480);             // 8192 B
    float (*Obuf)[68] = reinterpret_cast<float(*)[68]>(smem);          // epilogue alias, 17408 B

    const int tid  = threadIdx.x;
    const int lane = tid & 63;
    const int w    = tid >> 6;
    const int quad = lane >> 4;
    const int l16  = lane & 15;
    const int qt = blockIdx.x;     // 0..31
    const int h  = blockIdx.y;     // 0..11
    const int b  = blockIdx.z;     // 0..1

    // one-time mask preload
    #pragma unroll
    for (int i = 0; i < 8; i++) {
        int s = tid + i * 256;
        maskC[s] = amask[b * 2048 + s] ? (-SM_C * LOG2E) : -2.0e6f;
    }
    __syncthreads();

    const u16* Qbase = Qp + ((size_t)(b * 12 + h) * 2048 + qt * 64) * 64;
    const u16* Kb2   = Kp + (size_t)(b * 12 + h) * 2048 * 64 + (size_t)w * 32 * 64;
    const u16* Vb2   = Vt + (size_t)(b * 12 + h) * 64 * 2048 + (size_t)w * 32;

    // Q fragments for ALL 4 q-blocks (resident; used as B-operand for S^T)
    bf16x8 qfrag[4][2];
    #pragma unroll
    for (int qb = 0; qb < 4; qb++)
        #pragma unroll
        for (int kk = 0; kk < 2; kk++)
            qfrag[qb][kk] = *reinterpret_cast<const bf16x8*>(
                &Qbase[(qb * 16 + l16) * 64 + kk * 32 + quad * 8]);

    // ones B-fragment: B[n=0][k]=1 -> C col 0 = rowsum(P)
    bf16x8 onesf = {};
    if (l16 == 0) {
        #pragma unroll
        for (int i = 0; i < 8; i++) onesf[i] = (__bf16)1.0f;
    }

    f32x4 oacc[4][4] = {};   // [qb][d-block] partial over this wave's keys
    f32x4 sacc[4]    = {};   // [qb] partial rowsums (col 0)

    // preload st=0 K and V fragments
    bf16x8 kf[2][2], vf[4];
    #pragma unroll
    for (int ct = 0; ct < 2; ct++)
        #pragma unroll
        for (int kk = 0; kk < 2; kk++)
            kf[ct][kk] = *reinterpret_cast<const bf16x8*>(
                &Kb2[(size_t)(ct * 16 + l16) * 64 + kk * 32 + quad * 8]);
    #pragma unroll
    for (int cd = 0; cd < 4; cd++)
        vf[cd] = *reinterpret_cast<const bf16x8*>(
            &Vb2[(size_t)(cd * 16 + l16) * 2048 + quad * 8]);

    for (int st = 0; st < 16; st++) {
        const int stn = (st + 1) & 15;   // wrap: st=15 reloads st=0 (unused, in-bounds)

        // S^T = K·Q^T, ct-outer; reload kf[ct] right after its last use
        #pragma unroll
        for (int ct = 0; ct < 2; ct++) {
            f32x4 sv[4];
            #pragma unroll
            for (int qb = 0; qb < 4; qb++) {
                f32x4 s = {};
                s = __builtin_amdgcn_mfma_f32_16x16x32_bf16(kf[ct][0], qfrag[qb][0], s, 0, 0, 0);
                s = __builtin_amdgcn_mfma_f32_16x16x32_bf16(kf[ct][1], qfrag[qb][1], s, 0, 0, 0);
                sv[qb] = s;
            }
            // kf[ct] dead -> issue next-tile loads into the same registers
            #pragma unroll
            for (int kk = 0; kk < 2; kk++)
                kf[ct][kk] = *reinterpret_cast<const bf16x8*>(
                    &Kb2[(size_t)(stn * 128 + ct * 16 + l16) * 64 + kk * 32 + quad * 8]);

            f32x4 cc = *reinterpret_cast<const f32x4*>(
                &maskC[st * 128 + w * 32 + ct * 16 + quad * 4]);
            #pragma unroll
            for (int qb = 0; qb < 4; qb++) {
                union { u16 h[4]; uint2 v2; } pk;
                #pragma unroll
                for (int r = 0; r < 4; r++)
                    pk.h[r] = bfbits(__builtin_amdgcn_exp2f(__builtin_fmaf(sv[qb][r], K1, cc[r])));
                *reinterpret_cast<uint2*>(&Ps[w][qb * 16 + l16][ct * 16 + quad * 4]) = pk.v2;
            }
        }

        // read P as A-fragments (K-dim = wave's 32 keys); accumulate partials
        bf16x8 pf[4];
        #pragma unroll
        for (int qb = 0; qb < 4; qb++)
            pf[qb] = *reinterpret_cast<const bf16x8*>(&Ps[w][qb * 16 + l16][quad * 8]);
        #pragma unroll
        for (int qb = 0; qb < 4; qb++)
            sacc[qb] = __builtin_amdgcn_mfma_f32_16x16x32_bf16(pf[qb], onesf, sacc[qb], 0, 0, 0);
        #pragma unroll
        for (int qb = 0; qb < 4; qb++)
            #pragma unroll
            for (int cd = 0; cd < 4; cd++)
                oacc[qb][cd] = __builtin_amdgcn_mfma_f32_16x16x32_bf16(pf[qb], vf[cd], oacc[qb][cd], 0, 0, 0);

        // vf dead -> issue next-tile V loads into the same registers
        #pragma unroll
        for (int cd = 0; cd < 4; cd++)
            vf[cd] = *reinterpret_cast<const bf16x8*>(
                &Vb2[(size_t)(cd * 16 + l16) * 2048 + stn * 128 + quad * 8]);
    }

    // ---- cross-wave reduction of O partials and rowsums (Obuf aliases Ps) ----
    __syncthreads();
    for (int wv = 0; wv < 4; wv++) {
        if (w == wv) {
            #pragma unroll
            for (int qb = 0; qb < 4; qb++) {
                #pragma unroll
                for (int cd = 0; cd < 4; cd++)
                    #pragma unroll
                    for (int r = 0; r < 4; r++) {
                        float* cell = &Obuf[qb * 16 + quad * 4 + r][cd * 16 + l16];
                        if (wv == 0) *cell = oacc[qb][cd][r];
                        else         *cell += oacc[qb][cd][r];
                    }
                if (l16 == 0) {
                    #pragma unroll
                    for (int r = 0; r < 4; r++) {
                        float* cell = &Obuf[qb * 16 + quad * 4 + r][64];
                        if (wv == 0) *cell = sacc[qb][r];
                        else         *cell += sacc[qb][r];
                    }
                }
            }
        }
        __syncthreads();
    }

    // normalize + store (vectorized 4 cols per thread)
    #pragma unroll
    for (int g = 0; g < 4; g++) {
        int unit = tid + g * 256;          // 0..1023
        int row = unit >> 4;               // 0..63
        int c4  = (unit & 15) * 4;
        float rinv = 1.0f / Obuf[row][64];
        union { u16 h[4]; uint2 v; } o;
        #pragma unroll
        for (int j = 0; j < 4; j++)
            o.h[j] = bfbits(Obuf[row][c4 + j] * rinv);
        *reinterpret_cast<uint2*>(
            &Oatt[(size_t)(b * 2048 + qt * 64 + row) * 768 + h * 64 + c4]) = o.v;
    }
}

// ---------------------------------------------------------------------------
// LayerNorm over D=768: one WAVE per row (no cross-wave reduce, no barrier),
// float4 vectorized. 4 rows/block, grid 1024.
// ---------------------------------------------------------------------------
__global__ __launch_bounds__(256) void ln_kernel(
    float* __restrict__ X, const float* __restrict__ gamma,
    const float* __restrict__ beta)
{
    const int tid  = threadIdx.x;
    const int w    = tid >> 6;
    const int lane = tid & 63;
    const int row  = blockIdx.x * 4 + w;
    float* xr = X + (size_t)row * 768;

    float4 v[3];
    float s = 0.f, s2 = 0.f;
    #pragma unroll
    for (int i = 0; i < 3; i++) {
        v[i] = *reinterpret_cast<const float4*>(&xr[i * 256 + lane * 4]);
        s  += v[i].x + v[i].y + v[i].z + v[i].w;
        s2 += v[i].x * v[i].x + v[i].y * v[i].y + v[i].z * v[i].z + v[i].w * v[i].w;
    }
    #pragma unroll
    for (int off = 32; off >= 1; off >>= 1) {
        s  += __shfl_xor(s,  off, 64);
        s2 += __shfl_xor(s2, off, 64);
    }
    float mu  = s * (1.0f / 768.0f);
    float var = s2 * (1.0f / 768.0f) - mu * mu;
    float rstd = rsqrtf(var + 1e-5f);
    #pragma unroll
    for (int i = 0; i < 3; i++) {
        int c = i * 256 + lane * 4;
        float4 g  = *reinterpret_cast<const float4*>(&gamma[c]);
        float4 bt = *reinterpret_cast<const float4*>(&beta[c]);
        float4 o;
        o.x = (v[i].x - mu) * rstd * g.x + bt.x;
        o.y = (v[i].y - mu) * rstd * g.y + bt.y;
        o.z = (v[i].z - mu) * rstd * g.z + bt.z;
        o.w = (v[i].w - mu) * rstd * g.w + bt.w;
        *reinterpret_cast<float4*>(&xr[c]) = o;
    }
}

extern "C" void kernel_launch(void* const* d_in, const int* in_sizes, int n_in,
                              void* d_out, int out_size, void* d_ws, size_t ws_size,
                              hipStream_t stream)
{
    const float* q   = (const float*)d_in[0];
    const float* k   = (const float*)d_in[1];
    const float* v   = (const float*)d_in[2];
    const int*   am  = (const int*)d_in[3];
    const float* Wq  = (const float*)d_in[4];
    const float* Wk  = (const float*)d_in[5];
    const float* Wv  = (const float*)d_in[6];
    const float* W   = (const float*)d_in[7];
    const float* bb  = (const float*)d_in[8];
    const float* gam = (const float*)d_in[9];
    const float* bet = (const float*)d_in[10];

    u16* Qp  = (u16*)d_ws;
    u16* Kp  = Qp + (size_t)MR * DM;
    u16* Vt  = Kp + (size_t)MR * DM;
    u16* Oa  = Vt + (size_t)MR * DM;
    float* Xb = (float*)d_out;                     // pre-LN x; LN in place

    gemm_qkv<<<dim3(64, 12, 3), 256, 0, stream>>>(q, k, v, Wq, Wk, Wv, Qp, Kp, Vt);
    attn<<<dim3(32, 12, 2), 256, 0, stream>>>(Qp, Kp, Vt, am, Oa);
    gemm_out<<<dim3(64, 12), 256, 0, stream>>>(Oa, W, bb, q, Xb);
    ln_kernel<<<1024, 256, 0, stream>>>(Xb, gam, bet);
}